// Round 22
// baseline (119.905 us; speedup 1.0000x reference)
//
#include <hip/hip_runtime.h>
#include <hip/hip_fp16.h>
#include <math.h>

#define K 32
#define F 128
#define H 256
#define TAB 4096
#define QB 8
#define BMAX 16
#define RCUT2 100.0f
#define KBINS 64
#define BINCAP 2560
#define BCAP 128
#define FP 132   // padded LDS row stride
#define WRR 16   // rows per block in wtab

typedef _Float16 f16x8 __attribute__((ext_vector_type(8)));
typedef float f32x4 __attribute__((ext_vector_type(4)));

__device__ __forceinline__ float ssp(float x) {
    return fmaxf(x, 0.0f) + log1pf(expf(-fabsf(x))) - 0.69314718055994531f;
}

__device__ __forceinline__ float d2f4(float4 p, float qx, float qy, float qz) {
    float dx = qx - p.x;
    float dy = qy - p.y;
    float dz = qz - p.z;
    return fmaf(dz, dz, fmaf(dy, dy, dx * dx));
}

// ---------------- prep: seg bounds + pos pad + attr->fp16 + lin1 B-fragment swizzle ----------------
__global__ __launch_bounds__(256) void prep_kernel(const int* __restrict__ bc, int Nc,
                                                   int* __restrict__ ctx_start,
                                                   const float* __restrict__ posc,
                                                   float4* __restrict__ posc4,
                                                   const float* __restrict__ attr,
                                                   __half* __restrict__ attrh,
                                                   const float* __restrict__ lin1_w,
                                                   __half* __restrict__ bfragh,
                                                   int padB, int convB) {
    int blk = blockIdx.x;
    int tid = threadIdx.x;
    if (blk == 0) {
        if (tid <= BMAX) {
            int b = tid;
            int lo = 0, hi = Nc;
            while (lo < hi) {
                int mid = (lo + hi) >> 1;
                if (bc[mid] < b) lo = mid + 1; else hi = mid;
            }
            ctx_start[b] = lo;
        }
    } else if (blk <= padB) {
        int i = (blk - 1) * 256 + tid;
        if (i < Nc)
            posc4[i] = make_float4(posc[i * 3 + 0], posc[i * 3 + 1], posc[i * 3 + 2], 0.0f);
    } else if (blk <= padB + convB) {
        size_t base = ((size_t)(blk - 1 - padB) * 256 + tid) * 8;
        if (base < (size_t)Nc * H) {
            float4 v0 = *(const float4*)&attr[base];
            float4 v1 = *(const float4*)&attr[base + 4];
            __half2 h[4];
            h[0] = __floats2half2_rn(v0.x, v0.y);
            h[1] = __floats2half2_rn(v0.z, v0.w);
            h[2] = __floats2half2_rn(v1.x, v1.y);
            h[3] = __floats2half2_rn(v1.z, v1.w);
            *(float4*)&attrh[base] = *(float4*)h;
        }
    } else {
        // B-fragment swizzle: ts = t*8+s; element e = lane*8+j
        int ts = blk - 1 - padB - convB;     // 0..63
        int t = ts >> 3, s = ts & 7;
        for (int e = tid; e < 512; e += 256) {
            int l = e >> 3, j = e & 7;
            int k = s * 32 + (l >> 4) * 8 + j;
            int col = (l & 15) + 16 * t;
            bfragh[(size_t)ts * 512 + e] = __float2half(lin1_w[k * F + col]);
        }
    }
}

// ================= phase2 bodies (knn / wtab share LDS; feat uses none) =================

__device__ __forceinline__ void knn_body(char* smem, const float* __restrict__ posq,
                                         const float4* __restrict__ posc4,
                                         const int* __restrict__ bq,
                                         const int* __restrict__ ctx_start,
                                         int* __restrict__ nbr, int Nq,
                                         int blk, int tid) {
    unsigned char (*sbin)[BINCAP] = (unsigned char (*)[BINCAP])(smem);          // 10240
    int (*hist)[KBINS]            = (int (*)[KBINS])(smem + 10240);             // 1024
    unsigned (*bkey)[BCAP]        = (unsigned (*)[BCAP])(smem + 11264);         // 2048
    int (*bidx)[BCAP]             = (int (*)[BCAP])(smem + 13312);              // 2048
    int* s_nwin                   = (int*)(smem + 15360);
    int* s_nbnd                   = (int*)(smem + 15376);

    int lane = tid & 63;
    int w = tid >> 6;
    int q = blk * 4 + w;
    bool active = q < Nq;
    int qc = active ? q : 0;

    hist[w][lane] = 0;
    if (lane == 0) { s_nwin[w] = 0; s_nbnd[w] = 0; }

    float qx = posq[qc * 3 + 0];
    float qy = posq[qc * 3 + 1];
    float qz = posq[qc * 3 + 2];
    int b = bq[qc];
    int c0 = ctx_start[b];
    int c1 = ctx_start[b + 1];
    int seg = active ? (c1 - c0) : 0;
    __syncthreads();

    const float SCALE = (float)KBINS / RCUT2;
    int farc = -1;

    for (int i = lane; i < seg; i += 64) {
        float d2 = d2f4(posc4[c0 + i], qx, qy, qz);
        int bin = 255;
        if (d2 < RCUT2) {
            bin = (int)(d2 * SCALE);
            atomicAdd(&hist[w][bin], 1);
        }
        if (i < BINCAP) sbin[w][i] = (unsigned char)bin;
    }
    __syncthreads();

    int h = hist[w][lane];
    int inc = h;
#pragma unroll
    for (int off = 1; off < 64; off <<= 1) {
        int v = __shfl_up(inc, off);
        if (lane >= off) inc += v;
    }
    unsigned long long bal = __ballot(inc >= K);
    int T, below;
    if (bal) {
        T = __ffsll(bal) - 1;
        below = __shfl(inc, T) - __shfl(h, T);
    } else {
        T = KBINS;
        below = __shfl(inc, 63);
    }

    for (int i = lane; i < seg; i += 64) {
        int c = c0 + i;
        int bin;
        if (i < BINCAP) bin = sbin[w][i];
        else {
            float d2 = d2f4(posc4[c], qx, qy, qz);
            bin = (d2 < RCUT2) ? (int)(d2 * SCALE) : 255;
        }
        if (bin < T) {
            int p = atomicAdd(&s_nwin[w], 1);
            nbr[(size_t)q * K + p] = c;
        } else if (bin == T) {
            int p = atomicAdd(&s_nbnd[w], 1);
            if (p < BCAP) {
                float d2 = d2f4(posc4[c], qx, qy, qz);
                bkey[w][p] = __float_as_uint(d2);
                bidx[w][p] = c;
            }
        } else if (bin == 255) {
            farc = c;
        }
    }
#pragma unroll
    for (int off = 1; off < 64; off <<= 1) farc = max(farc, __shfl_xor(farc, off));
    if (farc < 0) farc = c0;
    __syncthreads();

    if (!active) return;
    int nb = min(s_nbnd[w], BCAP);
    int m = K - s_nwin[w];
    // pick m smallest by (d2, ctx_index): deterministic under atomic reordering.
    for (int it = 0; it < m; ++it) {
        unsigned long long bestkey = 0xFFFFFFFFFFFFFFFFull;
        int bestp = -1;
        for (int p = lane; p < nb; p += 64) {
            unsigned kk = bkey[w][p];
            if (kk != 0xFFFFFFFFu) {
                unsigned long long pk = ((unsigned long long)kk << 32) | (unsigned)bidx[w][p];
                if (pk < bestkey) { bestkey = pk; bestp = p; }
            }
        }
#pragma unroll
        for (int off = 1; off < 64; off <<= 1) {
            unsigned long long ok = __shfl_xor(bestkey, off);
            int op = __shfl_xor(bestp, off);
            if (ok < bestkey) { bestkey = ok; bestp = op; }
        }
        if (lane == 0) {
            if (bestp >= 0 && bestkey != 0xFFFFFFFFFFFFFFFFull) {
                nbr[(size_t)q * K + below + it] = (int)(bestkey & 0xFFFFFFFFu);
                bkey[w][bestp] = 0xFFFFFFFFu;
            } else {
                nbr[(size_t)q * K + below + it] = farc;   // pad: contributes 0
            }
        }
        __asm__ volatile("" ::: "memory");
    }
}

__device__ __forceinline__ void wtab_body(char* smem, const float* __restrict__ nn1_w,
                                          const float* __restrict__ nn1_b,
                                          const float* __restrict__ nn2_w,
                                          const float* __restrict__ nn2_b,
                                          __half2* __restrict__ wt2h,
                                          int blk, int tid) {
    float (*sg)[F] = (float (*)[F])smem;             // 8704
    float (*st)[F] = (float (*)[F])(smem + 8704);    // 8704
    int t0 = blk * WRR;
    int f = tid & (F - 1);
    int g = tid >> 7;

    const float delta = 10.0f / 127.0f;
    const float coeff = -0.5f / (delta * delta);
    float off = (float)f * delta;
    for (int r = g; r < 17; r += 2) {
        float dist = (float)(t0 + r) * (10.0f / (float)TAB);
        float d = dist - off;
        sg[r][f] = expf(coeff * d * d);
    }
    __syncthreads();

    float acc[9];
#pragma unroll
    for (int r = 0; r < 9; ++r) acc[r] = 0.0f;
    for (int j = 0; j < F; j += 4) {
        float w0 = nn1_w[(j + 0) * F + f];
        float w1 = nn1_w[(j + 1) * F + f];
        float w2 = nn1_w[(j + 2) * F + f];
        float w3 = nn1_w[(j + 3) * F + f];
#pragma unroll
        for (int r = 0; r < 9; ++r) {
            float4 a4 = *(const float4*)&sg[g * 8 + r][j];
            acc[r] = fmaf(a4.x, w0, acc[r]);
            acc[r] = fmaf(a4.y, w1, acc[r]);
            acc[r] = fmaf(a4.z, w2, acc[r]);
            acc[r] = fmaf(a4.w, w3, acc[r]);
        }
    }
    float b1 = nn1_b[f];
#pragma unroll
    for (int r = 0; r < 9; ++r) st[g * 8 + r][f] = ssp(acc[r] + b1);
    __syncthreads();

#pragma unroll
    for (int r = 0; r < 9; ++r) acc[r] = 0.0f;
    for (int j = 0; j < F; j += 4) {
        float w0 = nn2_w[(j + 0) * F + f];
        float w1 = nn2_w[(j + 1) * F + f];
        float w2 = nn2_w[(j + 2) * F + f];
        float w3 = nn2_w[(j + 3) * F + f];
#pragma unroll
        for (int r = 0; r < 9; ++r) {
            float4 a4 = *(const float4*)&st[g * 8 + r][j];
            acc[r] = fmaf(a4.x, w0, acc[r]);
            acc[r] = fmaf(a4.y, w1, acc[r]);
            acc[r] = fmaf(a4.z, w2, acc[r]);
            acc[r] = fmaf(a4.w, w3, acc[r]);
        }
    }
    float b2 = nn2_b[f];
#pragma unroll
    for (int i = 0; i < 8; ++i) {
        int t = t0 + g * 8 + i;
        wt2h[(size_t)t * F + f] = __floats2half2_rn(acc[i] + b2, acc[i + 1] + b2);
    }
}

// MFMA feat body: wave = 32 rows x 32 cols, 2x2 tiles x 8 k-steps
__device__ __forceinline__ void feat_body(const __half* __restrict__ attrh_,
                                          const __half* __restrict__ bfragh_,
                                          __half* __restrict__ ctx_feat, int Nc,
                                          int blk, int tid) {
    const _Float16* attrh = (const _Float16*)attrh_;
    const _Float16* bfragh = (const _Float16*)bfragh_;
    int wave = tid >> 6;
    int lane = tid & 63;
    int r0 = blk * 32;

    f32x4 acc[2][2] = {{{0.f,0.f,0.f,0.f},{0.f,0.f,0.f,0.f}},{{0.f,0.f,0.f,0.f},{0.f,0.f,0.f,0.f}}};

    int arow[2];
#pragma unroll
    for (int rt = 0; rt < 2; ++rt) {
        int row = r0 + rt * 16 + (lane & 15);
        arow[rt] = (row < Nc) ? row : (Nc - 1);
    }
    int kbase = (lane >> 4) * 8;

    for (int s = 0; s < 8; ++s) {
        f16x8 a0 = *(const f16x8*)(attrh + (size_t)arow[0] * H + s * 32 + kbase);
        f16x8 a1 = *(const f16x8*)(attrh + (size_t)arow[1] * H + s * 32 + kbase);
#pragma unroll
        for (int ct = 0; ct < 2; ++ct) {
            int t = 2 * wave + ct;
            f16x8 b = *(const f16x8*)(bfragh + ((size_t)(t * 8 + s) * 64 + lane) * 8);
            acc[0][ct] = __builtin_amdgcn_mfma_f32_16x16x32_f16(a0, b, acc[0][ct], 0, 0, 0);
            acc[1][ct] = __builtin_amdgcn_mfma_f32_16x16x32_f16(a1, b, acc[1][ct], 0, 0, 0);
        }
    }

    // C layout: col = lane&15, row = (lane>>4)*4 + j
#pragma unroll
    for (int rt = 0; rt < 2; ++rt) {
#pragma unroll
        for (int ct = 0; ct < 2; ++ct) {
            int col = (2 * wave + ct) * 16 + (lane & 15);
#pragma unroll
            for (int j = 0; j < 4; ++j) {
                int row = r0 + rt * 16 + (lane >> 4) * 4 + j;
                if (row < Nc)
                    ctx_feat[(size_t)row * F + col] = __float2half(acc[rt][ct][j]);
            }
        }
    }
}

// partition order: knn (latency-bound) first, wtab, feat (MFMA)
__global__ __launch_bounds__(256) void phase2_kernel(const float* __restrict__ posq,
                                                     const float4* __restrict__ posc4,
                                                     const int* __restrict__ bq,
                                                     const int* __restrict__ ctx_start,
                                                     int* __restrict__ nbr, int Nq,
                                                     const float* __restrict__ nn1_w,
                                                     const float* __restrict__ nn1_b,
                                                     const float* __restrict__ nn2_w,
                                                     const float* __restrict__ nn2_b,
                                                     __half2* __restrict__ wt2h,
                                                     const __half* __restrict__ attrh,
                                                     const __half* __restrict__ bfragh,
                                                     __half* __restrict__ ctx_feat, int Nc,
                                                     int knnB, int wtabB) {
    __shared__ __align__(16) char smem[17408];
    int blk = blockIdx.x;
    int tid = threadIdx.x;
    if (blk < knnB) {
        knn_body(smem, posq, posc4, bq, ctx_start, nbr, Nq, blk, tid);
    } else if (blk < knnB + wtabB) {
        wtab_body(smem, nn1_w, nn1_b, nn2_w, nn2_b, wt2h, blk - knnB, tid);
    } else {
        feat_body(attrh, bfragh, ctx_feat, Nc, blk - knnB - wtabB, tid);
    }
}

// ================= fused agg + head: f-quad agg over fp16 tables =================
__global__ __launch_bounds__(256) void agghead_kernel(const float* __restrict__ posq,
                                                      const float4* __restrict__ posc4,
                                                      const int* __restrict__ nbr,
                                                      const __half* __restrict__ ctx_feat,
                                                      const __half2* __restrict__ wt2h,
                                                      const float* __restrict__ lin2_w,
                                                      const float* __restrict__ lin2_b,
                                                      const float* __restrict__ cls1_w,
                                                      const float* __restrict__ cls1_b,
                                                      const float* __restrict__ cls2_w,
                                                      const float* __restrict__ cls2_b,
                                                      const float* __restrict__ prop1_w,
                                                      const float* __restrict__ prop1_b,
                                                      const float* __restrict__ prop2_w,
                                                      const float* __restrict__ prop2_b,
                                                      float* __restrict__ out_cls,
                                                      float* __restrict__ out_ind, int Nq) {
    const int QH = QB / 2;
    int q0 = blockIdx.x * QB;
    int tid = threadIdx.x;

    __shared__ __align__(16) char sm[12672];
    float4* sedge      = (float4*)sm;                       // [256]
    float (*sa)[F]     = (float (*)[F])(sm + 4096);         // [8][128]
    float* ssc         = (float*)(sm + 8192);               // [8]
    float (*sc1)[FP]   = (float (*)[FP])(sm);               // alias (after stage A)
    float (*sp1)[FP]   = (float (*)[FP])(sm + 4224);        // alias
    float (*sy)[FP]    = (float (*)[FP])(sm + 8448);        // [8][132]

    // ---- per-edge stage ----
    {
        int qq = tid >> 5;
        int q = q0 + qq;
        if (q >= Nq) q = Nq - 1;
        int j = nbr[(size_t)q * K + (tid & 31)];
        float4 p = posc4[j];
        float dx = posq[q * 3 + 0] - p.x;
        float dy = posq[q * 3 + 1] - p.y;
        float dz = posq[q * 3 + 2] - p.z;
        float dist = sqrtf(fmaf(dz, dz, fmaf(dy, dy, dx * dx)));
        float C = 0.0f, fr = 0.0f;
        int i0 = 0;
        if (dist <= 10.0f) {
            C = 0.5f * (cosf(dist * 0.31415926535897931f) + 1.0f);
            float u = dist * ((float)TAB / 10.0f);
            i0 = (int)u;
            if (i0 > TAB - 1) i0 = TAB - 1;
            fr = u - (float)i0;
        }
        sedge[tid] = make_float4(C, fr, __int_as_float(i0 * F), __int_as_float(j * F));
        float cs = C;
#pragma unroll
        for (int off = 1; off < 32; off <<= 1) cs += __shfl_xor(cs, off);
        if ((tid & 31) == 0) ssc[qq] = cs;
    }
    __syncthreads();

    // ---- agg: f-quad per thread; 16B wt2 + 8B ctx per k covers 4 f ----
    {
        int fq = tid & 31;          // f0 = 4*fq
        int qq = tid >> 5;          // query 0..7
        int f0 = fq * 4;
        const __half2* w2b = wt2h + f0;
        const __half* cfb = ctx_feat + f0;
        float acc[4] = {0.0f, 0.0f, 0.0f, 0.0f};
#pragma unroll 4
        for (int k = 0; k < K; ++k) {
            float4 e4 = sedge[qq * K + k];
            float C = e4.x, fr = e4.y;
            int i0f = __float_as_int(e4.z);
            int jf = __float_as_int(e4.w);
            __half2 w[4];
            *(float4*)w = *(const float4*)(w2b + i0f);     // pairs for f0..f0+3
            __half2 ah[2];
            *(float2*)ah = *(const float2*)(cfb + jf);     // ctx f0..f0+3
            float2 w0 = __half22float2(w[0]);
            float2 w1 = __half22float2(w[1]);
            float2 w2 = __half22float2(w[2]);
            float2 w3 = __half22float2(w[3]);
            float2 a0 = __half22float2(ah[0]);
            float2 a1 = __half22float2(ah[1]);
            float W0 = fmaf(fr, w0.y - w0.x, w0.x);
            float W1 = fmaf(fr, w1.y - w1.x, w1.x);
            float W2 = fmaf(fr, w2.y - w2.x, w2.x);
            float W3 = fmaf(fr, w3.y - w3.x, w3.x);
            acc[0] = fmaf(C * W0, a0.x, acc[0]);
            acc[1] = fmaf(C * W1, a0.y, acc[1]);
            acc[2] = fmaf(C * W2, a1.x, acc[2]);
            acc[3] = fmaf(C * W3, a1.y, acc[3]);
        }
        *(float4*)&sa[qq][f0] = make_float4(acc[0], acc[1], acc[2], acc[3]);
    }
    __syncthreads();

    int f = tid & (F - 1);
    int g = tid >> 7;

    // ---- head stage A ----
    {
        float y[QH];
        float lb = lin2_b[f];
#pragma unroll
        for (int i = 0; i < QH; ++i) y[i] = ssc[g * QH + i] * lb;
        for (int j = 0; j < F; j += 4) {
            float w0 = lin2_w[(j + 0) * F + f];
            float w1 = lin2_w[(j + 1) * F + f];
            float w2 = lin2_w[(j + 2) * F + f];
            float w3 = lin2_w[(j + 3) * F + f];
#pragma unroll
            for (int i = 0; i < QH; ++i) {
                float4 a4 = *(const float4*)&sa[g * QH + i][j];
                y[i] = fmaf(a4.x, w0, y[i]);
                y[i] = fmaf(a4.y, w1, y[i]);
                y[i] = fmaf(a4.z, w2, y[i]);
                y[i] = fmaf(a4.w, w3, y[i]);
            }
        }
#pragma unroll
        for (int i = 0; i < QH; ++i) sy[g * QH + i][f] = y[i];
    }
    __syncthreads();   // sa/sedge/ssc dead; sc1/sp1 may overwrite

    // ---- head stage B ----
    {
        float c1[QH], p1[QH];
        float cb = cls1_b[f], pb = prop1_b[f];
#pragma unroll
        for (int i = 0; i < QH; ++i) { c1[i] = cb; p1[i] = pb; }
        for (int j = 0; j < F; j += 4) {
            float wc0 = cls1_w[(j + 0) * F + f];
            float wc1 = cls1_w[(j + 1) * F + f];
            float wc2 = cls1_w[(j + 2) * F + f];
            float wc3 = cls1_w[(j + 3) * F + f];
            float wp0 = prop1_w[(j + 0) * F + f];
            float wp1 = prop1_w[(j + 1) * F + f];
            float wp2 = prop1_w[(j + 2) * F + f];
            float wp3 = prop1_w[(j + 3) * F + f];
#pragma unroll
            for (int i = 0; i < QH; ++i) {
                float4 y4 = *(const float4*)&sy[g * QH + i][j];
                c1[i] = fmaf(y4.x, wc0, c1[i]);
                c1[i] = fmaf(y4.y, wc1, c1[i]);
                c1[i] = fmaf(y4.z, wc2, c1[i]);
                c1[i] = fmaf(y4.w, wc3, c1[i]);
                p1[i] = fmaf(y4.x, wp0, p1[i]);
                p1[i] = fmaf(y4.y, wp1, p1[i]);
                p1[i] = fmaf(y4.z, wp2, p1[i]);
                p1[i] = fmaf(y4.w, wp3, p1[i]);
            }
        }
#pragma unroll
        for (int i = 0; i < QH; ++i) {
            sc1[g * QH + i][f] = ssp(c1[i]);
            sp1[g * QH + i][f] = ssp(p1[i]);
        }
    }
    __syncthreads();

    // ---- tails ----
    {
        int qq = tid >> 5;
        int c = tid & 31;
        int q = q0 + qq;
        if (q < Nq && c < 15) {
            if (c < 7) {
                float acc = cls2_b[c];
                for (int j = 0; j < F; ++j) acc = fmaf(sc1[qq][j], cls2_w[j * 7 + c], acc);
                out_cls[(size_t)q * 7 + c] = acc;
            } else {
                int cc = c - 7;
                float acc = prop2_b[cc];
                for (int j = 0; j < F; ++j) acc = fmaf(sp1[qq][j], prop2_w[j * 8 + cc], acc);
                out_ind[(size_t)q * 8 + cc] = acc;
            }
        }
    }
}

extern "C" void kernel_launch(void* const* d_in, const int* in_sizes, int n_in,
                              void* d_out, int out_size, void* d_ws, size_t ws_size,
                              hipStream_t stream) {
    const float* posq   = (const float*)d_in[0];
    const float* posc   = (const float*)d_in[1];
    const float* attr   = (const float*)d_in[2];
    const int*   bq     = (const int*)d_in[3];
    const int*   bc     = (const int*)d_in[4];
    const float* lin1_w = (const float*)d_in[5];
    const float* lin2_w = (const float*)d_in[6];
    const float* lin2_b = (const float*)d_in[7];
    const float* nn1_w  = (const float*)d_in[8];
    const float* nn1_b  = (const float*)d_in[9];
    const float* nn2_w  = (const float*)d_in[10];
    const float* nn2_b  = (const float*)d_in[11];
    const float* cls1_w = (const float*)d_in[12];
    const float* cls1_b = (const float*)d_in[13];
    const float* cls2_w = (const float*)d_in[14];
    const float* cls2_b = (const float*)d_in[15];
    const float* prop1_w = (const float*)d_in[16];
    const float* prop1_b = (const float*)d_in[17];
    const float* prop2_w = (const float*)d_in[18];
    const float* prop2_b = (const float*)d_in[19];
    (void)n_in; (void)out_size; (void)ws_size;

    int Nq = in_sizes[0] / 3;
    int Nc = in_sizes[1] / 3;

    char* ws = (char*)d_ws;
    size_t off = 0;
    auto alloc = [&](size_t bytes) {
        off = (off + 255) & ~(size_t)255;
        void* p = ws + off;
        off += bytes;
        return p;
    };
    int*     ctx_start = (int*)alloc((BMAX + 1) * sizeof(int));
    int*     nbr       = (int*)alloc((size_t)Nq * K * sizeof(int));
    __half*  ctx_feat  = (__half*)alloc((size_t)Nc * F * sizeof(__half));
    __half2* wt2h      = (__half2*)alloc((size_t)TAB * F * sizeof(__half2));
    float4*  posc4     = (float4*)alloc((size_t)Nc * sizeof(float4));
    __half*  attrh     = (__half*)alloc((size_t)Nc * H * sizeof(__half));
    __half*  bfragh    = (__half*)alloc((size_t)64 * 512 * sizeof(__half));

    float* out_cls = (float*)d_out;
    float* out_ind = out_cls + (size_t)Nq * 7;

    int padB  = (Nc + 255) / 256;
    int convB = (int)(((size_t)Nc * H / 8 + 255) / 256);
    int swzB  = 64;
    int featB = (Nc + 31) / 32;             // 512
    int knnB  = (Nq + 3) / 4;               // 2048
    int wtabB = TAB / WRR;                  // 256

    prep_kernel<<<dim3(1 + padB + convB + swzB), dim3(256), 0, stream>>>(
        bc, Nc, ctx_start, posc, posc4, attr, attrh, lin1_w, bfragh, padB, convB);
    phase2_kernel<<<dim3(knnB + wtabB + featB), dim3(256), 0, stream>>>(
        posq, posc4, bq, ctx_start, nbr, Nq,
        nn1_w, nn1_b, nn2_w, nn2_b, wt2h,
        attrh, bfragh, ctx_feat, Nc, knnB, wtabB);
    agghead_kernel<<<dim3((Nq + QB - 1) / QB), dim3(256), 0, stream>>>(
        posq, posc4, nbr, ctx_feat, wt2h,
        lin2_w, lin2_b, cls1_w, cls1_b, cls2_w, cls2_b,
        prop1_w, prop1_b, prop2_w, prop2_b, out_cls, out_ind, Nq);
}

// Round 23
// 109.548 us; speedup vs baseline: 1.0945x; 1.0945x over previous
//
#include <hip/hip_runtime.h>
#include <hip/hip_fp16.h>
#include <math.h>

#define K 32
#define F 128
#define H 256
#define TAB 4096
#define QB 8
#define BMAX 16
#define RCUT2 100.0f
#define KBINS 64
#define BINCAP 2560
#define BCAP 128
#define FP 132   // padded LDS row stride
#define WRR 16   // rows per block in wtab

typedef _Float16 f16x8 __attribute__((ext_vector_type(8)));
typedef float f32x4 __attribute__((ext_vector_type(4)));

__device__ __forceinline__ float ssp(float x) {
    return fmaxf(x, 0.0f) + log1pf(expf(-fabsf(x))) - 0.69314718055994531f;
}

__device__ __forceinline__ float d2f4(float4 p, float qx, float qy, float qz) {
    float dx = qx - p.x;
    float dy = qy - p.y;
    float dz = qz - p.z;
    return fmaf(dz, dz, fmaf(dy, dy, dx * dx));
}

// ---------------- prep: seg bounds + pos pad + attr->fp16 + lin1 B-fragment swizzle ----------------
__global__ __launch_bounds__(256) void prep_kernel(const int* __restrict__ bc, int Nc,
                                                   int* __restrict__ ctx_start,
                                                   const float* __restrict__ posc,
                                                   float4* __restrict__ posc4,
                                                   const float* __restrict__ attr,
                                                   __half* __restrict__ attrh,
                                                   const float* __restrict__ lin1_w,
                                                   __half* __restrict__ bfragh,
                                                   int padB, int convB) {
    int blk = blockIdx.x;
    int tid = threadIdx.x;
    if (blk == 0) {
        if (tid <= BMAX) {
            int b = tid;
            int lo = 0, hi = Nc;
            while (lo < hi) {
                int mid = (lo + hi) >> 1;
                if (bc[mid] < b) lo = mid + 1; else hi = mid;
            }
            ctx_start[b] = lo;
        }
    } else if (blk <= padB) {
        int i = (blk - 1) * 256 + tid;
        if (i < Nc)
            posc4[i] = make_float4(posc[i * 3 + 0], posc[i * 3 + 1], posc[i * 3 + 2], 0.0f);
    } else if (blk <= padB + convB) {
        size_t base = ((size_t)(blk - 1 - padB) * 256 + tid) * 8;
        if (base < (size_t)Nc * H) {
            float4 v0 = *(const float4*)&attr[base];
            float4 v1 = *(const float4*)&attr[base + 4];
            __half2 h[4];
            h[0] = __floats2half2_rn(v0.x, v0.y);
            h[1] = __floats2half2_rn(v0.z, v0.w);
            h[2] = __floats2half2_rn(v1.x, v1.y);
            h[3] = __floats2half2_rn(v1.z, v1.w);
            *(float4*)&attrh[base] = *(float4*)h;
        }
    } else {
        // B-fragment swizzle: ts = t*8+s; element e = lane*8+j
        int ts = blk - 1 - padB - convB;     // 0..63
        int t = ts >> 3, s = ts & 7;
        for (int e = tid; e < 512; e += 256) {
            int l = e >> 3, j = e & 7;
            int k = s * 32 + (l >> 4) * 8 + j;
            int col = (l & 15) + 16 * t;
            bfragh[(size_t)ts * 512 + e] = __float2half(lin1_w[k * F + col]);
        }
    }
}

// ---------------- feat: MFMA fp16 GEMM. 512 blocks x 4 waves; wave = 32r x 32c ----------------
__global__ __launch_bounds__(256) void feat_kernel(const __half* __restrict__ attrh_,
                                                   const __half* __restrict__ bfragh_,
                                                   __half* __restrict__ ctx_feat, int Nc) {
    const _Float16* attrh = (const _Float16*)attrh_;
    const _Float16* bfragh = (const _Float16*)bfragh_;
    int tid = threadIdx.x;
    int wave = tid >> 6;
    int lane = tid & 63;
    int r0 = blockIdx.x * 32;

    f32x4 acc[2][2] = {{{0.f,0.f,0.f,0.f},{0.f,0.f,0.f,0.f}},{{0.f,0.f,0.f,0.f},{0.f,0.f,0.f,0.f}}};

    int arow[2];
#pragma unroll
    for (int rt = 0; rt < 2; ++rt) {
        int row = r0 + rt * 16 + (lane & 15);
        arow[rt] = (row < Nc) ? row : (Nc - 1);
    }
    int kbase = (lane >> 4) * 8;

    for (int s = 0; s < 8; ++s) {
        f16x8 a0 = *(const f16x8*)(attrh + (size_t)arow[0] * H + s * 32 + kbase);
        f16x8 a1 = *(const f16x8*)(attrh + (size_t)arow[1] * H + s * 32 + kbase);
#pragma unroll
        for (int ct = 0; ct < 2; ++ct) {
            int t = 2 * wave + ct;
            f16x8 b = *(const f16x8*)(bfragh + ((size_t)(t * 8 + s) * 64 + lane) * 8);
            acc[0][ct] = __builtin_amdgcn_mfma_f32_16x16x32_f16(a0, b, acc[0][ct], 0, 0, 0);
            acc[1][ct] = __builtin_amdgcn_mfma_f32_16x16x32_f16(a1, b, acc[1][ct], 0, 0, 0);
        }
    }

    // C layout: col = lane&15, row = (lane>>4)*4 + j
#pragma unroll
    for (int rt = 0; rt < 2; ++rt) {
#pragma unroll
        for (int ct = 0; ct < 2; ++ct) {
            int col = (2 * wave + ct) * 16 + (lane & 15);
#pragma unroll
            for (int j = 0; j < 4; ++j) {
                int row = r0 + rt * 16 + (lane >> 4) * 4 + j;
                if (row < Nc)
                    ctx_feat[(size_t)row * F + col] = __float2half(acc[rt][ct][j]);
            }
        }
    }
}

// ---------------- knn ----------------
__global__ __launch_bounds__(256) void knn_kernel(const float* __restrict__ posq,
                                                  const float4* __restrict__ posc4,
                                                  const int* __restrict__ bq,
                                                  const int* __restrict__ ctx_start,
                                                  int* __restrict__ nbr, int Nq) {
    __shared__ unsigned char sbin[4][BINCAP];
    __shared__ int hist[4][KBINS];
    __shared__ unsigned bkey[4][BCAP];
    __shared__ int bidx[4][BCAP];
    __shared__ int s_nwin[4], s_nbnd[4];

    int tid = threadIdx.x;
    int lane = tid & 63;
    int w = tid >> 6;
    int q = blockIdx.x * 4 + w;
    bool active = q < Nq;
    int qc = active ? q : 0;

    hist[w][lane] = 0;
    if (lane == 0) { s_nwin[w] = 0; s_nbnd[w] = 0; }

    float qx = posq[qc * 3 + 0];
    float qy = posq[qc * 3 + 1];
    float qz = posq[qc * 3 + 2];
    int b = bq[qc];
    int c0 = ctx_start[b];
    int c1 = ctx_start[b + 1];
    int seg = active ? (c1 - c0) : 0;
    __syncthreads();

    const float SCALE = (float)KBINS / RCUT2;
    int farc = -1;

    for (int i = lane; i < seg; i += 64) {
        float d2 = d2f4(posc4[c0 + i], qx, qy, qz);
        int bin = 255;
        if (d2 < RCUT2) {
            bin = (int)(d2 * SCALE);
            atomicAdd(&hist[w][bin], 1);
        }
        if (i < BINCAP) sbin[w][i] = (unsigned char)bin;
    }
    __syncthreads();

    int h = hist[w][lane];
    int inc = h;
#pragma unroll
    for (int off = 1; off < 64; off <<= 1) {
        int v = __shfl_up(inc, off);
        if (lane >= off) inc += v;
    }
    unsigned long long bal = __ballot(inc >= K);
    int T, below;
    if (bal) {
        T = __ffsll(bal) - 1;
        below = __shfl(inc, T) - __shfl(h, T);
    } else {
        T = KBINS;
        below = __shfl(inc, 63);
    }

    for (int i = lane; i < seg; i += 64) {
        int c = c0 + i;
        int bin;
        if (i < BINCAP) bin = sbin[w][i];
        else {
            float d2 = d2f4(posc4[c], qx, qy, qz);
            bin = (d2 < RCUT2) ? (int)(d2 * SCALE) : 255;
        }
        if (bin < T) {
            int p = atomicAdd(&s_nwin[w], 1);
            nbr[(size_t)q * K + p] = c;
        } else if (bin == T) {
            int p = atomicAdd(&s_nbnd[w], 1);
            if (p < BCAP) {
                float d2 = d2f4(posc4[c], qx, qy, qz);
                bkey[w][p] = __float_as_uint(d2);
                bidx[w][p] = c;
            }
        } else if (bin == 255) {
            farc = c;
        }
    }
#pragma unroll
    for (int off = 1; off < 64; off <<= 1) farc = max(farc, __shfl_xor(farc, off));
    if (farc < 0) farc = c0;
    __syncthreads();

    if (!active) return;
    int nb = min(s_nbnd[w], BCAP);
    int m = K - s_nwin[w];
    // pick m smallest by (d2, ctx_index): deterministic under atomic reordering,
    // matches jax top_k stable lowest-index tie-break.
    for (int it = 0; it < m; ++it) {
        unsigned long long bestkey = 0xFFFFFFFFFFFFFFFFull;
        int bestp = -1;
        for (int p = lane; p < nb; p += 64) {
            unsigned kk = bkey[w][p];
            if (kk != 0xFFFFFFFFu) {
                unsigned long long pk = ((unsigned long long)kk << 32) | (unsigned)bidx[w][p];
                if (pk < bestkey) { bestkey = pk; bestp = p; }
            }
        }
#pragma unroll
        for (int off = 1; off < 64; off <<= 1) {
            unsigned long long ok = __shfl_xor(bestkey, off);
            int op = __shfl_xor(bestp, off);
            if (ok < bestkey) { bestkey = ok; bestp = op; }
        }
        if (lane == 0) {
            if (bestp >= 0 && bestkey != 0xFFFFFFFFFFFFFFFFull) {
                nbr[(size_t)q * K + below + it] = (int)(bestkey & 0xFFFFFFFFu);
                bkey[w][bestp] = 0xFFFFFFFFu;
            } else {
                nbr[(size_t)q * K + below + it] = farc;   // pad: contributes 0
            }
        }
        __asm__ volatile("" ::: "memory");
    }
}

// ---------------- wtab: half2 lerp table ----------------
__global__ __launch_bounds__(256) void wtab_kernel(const float* __restrict__ nn1_w,
                                                   const float* __restrict__ nn1_b,
                                                   const float* __restrict__ nn2_w,
                                                   const float* __restrict__ nn2_b,
                                                   __half2* __restrict__ wt2h) {
    __shared__ float sg[17][F];
    __shared__ float st[17][F];
    int t0 = blockIdx.x * WRR;
    int tid = threadIdx.x;
    int f = tid & (F - 1);
    int g = tid >> 7;

    const float delta = 10.0f / 127.0f;
    const float coeff = -0.5f / (delta * delta);
    float off = (float)f * delta;
    for (int r = g; r < 17; r += 2) {
        float dist = (float)(t0 + r) * (10.0f / (float)TAB);
        float d = dist - off;
        sg[r][f] = expf(coeff * d * d);
    }
    __syncthreads();

    float acc[9];
#pragma unroll
    for (int r = 0; r < 9; ++r) acc[r] = 0.0f;
    for (int j = 0; j < F; j += 4) {
        float w0 = nn1_w[(j + 0) * F + f];
        float w1 = nn1_w[(j + 1) * F + f];
        float w2 = nn1_w[(j + 2) * F + f];
        float w3 = nn1_w[(j + 3) * F + f];
#pragma unroll
        for (int r = 0; r < 9; ++r) {
            float4 a4 = *(const float4*)&sg[g * 8 + r][j];
            acc[r] = fmaf(a4.x, w0, acc[r]);
            acc[r] = fmaf(a4.y, w1, acc[r]);
            acc[r] = fmaf(a4.z, w2, acc[r]);
            acc[r] = fmaf(a4.w, w3, acc[r]);
        }
    }
    float b1 = nn1_b[f];
#pragma unroll
    for (int r = 0; r < 9; ++r) st[g * 8 + r][f] = ssp(acc[r] + b1);
    __syncthreads();

#pragma unroll
    for (int r = 0; r < 9; ++r) acc[r] = 0.0f;
    for (int j = 0; j < F; j += 4) {
        float w0 = nn2_w[(j + 0) * F + f];
        float w1 = nn2_w[(j + 1) * F + f];
        float w2 = nn2_w[(j + 2) * F + f];
        float w3 = nn2_w[(j + 3) * F + f];
#pragma unroll
        for (int r = 0; r < 9; ++r) {
            float4 a4 = *(const float4*)&st[g * 8 + r][j];
            acc[r] = fmaf(a4.x, w0, acc[r]);
            acc[r] = fmaf(a4.y, w1, acc[r]);
            acc[r] = fmaf(a4.z, w2, acc[r]);
            acc[r] = fmaf(a4.w, w3, acc[r]);
        }
    }
    float b2 = nn2_b[f];
#pragma unroll
    for (int i = 0; i < 8; ++i) {
        int t = t0 + g * 8 + i;
        wt2h[(size_t)t * F + f] = __floats2half2_rn(acc[i] + b2, acc[i + 1] + b2);
    }
}

// ================= fused agg + head: f-quad agg over fp16 tables =================
__global__ __launch_bounds__(256) void agghead_kernel(const float* __restrict__ posq,
                                                      const float4* __restrict__ posc4,
                                                      const int* __restrict__ nbr,
                                                      const __half* __restrict__ ctx_feat,
                                                      const __half2* __restrict__ wt2h,
                                                      const float* __restrict__ lin2_w,
                                                      const float* __restrict__ lin2_b,
                                                      const float* __restrict__ cls1_w,
                                                      const float* __restrict__ cls1_b,
                                                      const float* __restrict__ cls2_w,
                                                      const float* __restrict__ cls2_b,
                                                      const float* __restrict__ prop1_w,
                                                      const float* __restrict__ prop1_b,
                                                      const float* __restrict__ prop2_w,
                                                      const float* __restrict__ prop2_b,
                                                      float* __restrict__ out_cls,
                                                      float* __restrict__ out_ind, int Nq) {
    const int QH = QB / 2;
    int q0 = blockIdx.x * QB;
    int tid = threadIdx.x;

    __shared__ __align__(16) char sm[12672];
    float4* sedge      = (float4*)sm;                       // [256]
    float (*sa)[F]     = (float (*)[F])(sm + 4096);         // [8][128]
    float* ssc         = (float*)(sm + 8192);               // [8]
    float (*sc1)[FP]   = (float (*)[FP])(sm);               // alias (after stage A)
    float (*sp1)[FP]   = (float (*)[FP])(sm + 4224);        // alias
    float (*sy)[FP]    = (float (*)[FP])(sm + 8448);        // [8][132]

    // ---- per-edge stage ----
    {
        int qq = tid >> 5;
        int q = q0 + qq;
        if (q >= Nq) q = Nq - 1;
        int j = nbr[(size_t)q * K + (tid & 31)];
        float4 p = posc4[j];
        float dx = posq[q * 3 + 0] - p.x;
        float dy = posq[q * 3 + 1] - p.y;
        float dz = posq[q * 3 + 2] - p.z;
        float dist = sqrtf(fmaf(dz, dz, fmaf(dy, dy, dx * dx)));
        float C = 0.0f, fr = 0.0f;
        int i0 = 0;
        if (dist <= 10.0f) {
            C = 0.5f * (cosf(dist * 0.31415926535897931f) + 1.0f);
            float u = dist * ((float)TAB / 10.0f);
            i0 = (int)u;
            if (i0 > TAB - 1) i0 = TAB - 1;
            fr = u - (float)i0;
        }
        sedge[tid] = make_float4(C, fr, __int_as_float(i0 * F), __int_as_float(j * F));
        float cs = C;
#pragma unroll
        for (int off = 1; off < 32; off <<= 1) cs += __shfl_xor(cs, off);
        if ((tid & 31) == 0) ssc[qq] = cs;
    }
    __syncthreads();

    // ---- agg: f-quad per thread; 16B wt2 + 8B ctx per k covers 4 f ----
    {
        int fq = tid & 31;          // f0 = 4*fq
        int qq = tid >> 5;          // query 0..7
        int f0 = fq * 4;
        const __half2* w2b = wt2h + f0;
        const __half* cfb = ctx_feat + f0;
        float acc[4] = {0.0f, 0.0f, 0.0f, 0.0f};
#pragma unroll 4
        for (int k = 0; k < K; ++k) {
            float4 e4 = sedge[qq * K + k];
            float C = e4.x, fr = e4.y;
            int i0f = __float_as_int(e4.z);
            int jf = __float_as_int(e4.w);
            __half2 w[4];
            *(float4*)w = *(const float4*)(w2b + i0f);     // pairs for f0..f0+3
            __half2 ah[2];
            *(float2*)ah = *(const float2*)(cfb + jf);     // ctx f0..f0+3
            float2 w0 = __half22float2(w[0]);
            float2 w1 = __half22float2(w[1]);
            float2 w2 = __half22float2(w[2]);
            float2 w3 = __half22float2(w[3]);
            float2 a0 = __half22float2(ah[0]);
            float2 a1 = __half22float2(ah[1]);
            float W0 = fmaf(fr, w0.y - w0.x, w0.x);
            float W1 = fmaf(fr, w1.y - w1.x, w1.x);
            float W2 = fmaf(fr, w2.y - w2.x, w2.x);
            float W3 = fmaf(fr, w3.y - w3.x, w3.x);
            acc[0] = fmaf(C * W0, a0.x, acc[0]);
            acc[1] = fmaf(C * W1, a0.y, acc[1]);
            acc[2] = fmaf(C * W2, a1.x, acc[2]);
            acc[3] = fmaf(C * W3, a1.y, acc[3]);
        }
        *(float4*)&sa[qq][f0] = make_float4(acc[0], acc[1], acc[2], acc[3]);
    }
    __syncthreads();

    int f = tid & (F - 1);
    int g = tid >> 7;

    // ---- head stage A ----
    {
        float y[QH];
        float lb = lin2_b[f];
#pragma unroll
        for (int i = 0; i < QH; ++i) y[i] = ssc[g * QH + i] * lb;
        for (int j = 0; j < F; j += 4) {
            float w0 = lin2_w[(j + 0) * F + f];
            float w1 = lin2_w[(j + 1) * F + f];
            float w2 = lin2_w[(j + 2) * F + f];
            float w3 = lin2_w[(j + 3) * F + f];
#pragma unroll
            for (int i = 0; i < QH; ++i) {
                float4 a4 = *(const float4*)&sa[g * QH + i][j];
                y[i] = fmaf(a4.x, w0, y[i]);
                y[i] = fmaf(a4.y, w1, y[i]);
                y[i] = fmaf(a4.z, w2, y[i]);
                y[i] = fmaf(a4.w, w3, y[i]);
            }
        }
#pragma unroll
        for (int i = 0; i < QH; ++i) sy[g * QH + i][f] = y[i];
    }
    __syncthreads();   // sa/sedge/ssc dead; sc1/sp1 may overwrite

    // ---- head stage B ----
    {
        float c1[QH], p1[QH];
        float cb = cls1_b[f], pb = prop1_b[f];
#pragma unroll
        for (int i = 0; i < QH; ++i) { c1[i] = cb; p1[i] = pb; }
        for (int j = 0; j < F; j += 4) {
            float wc0 = cls1_w[(j + 0) * F + f];
            float wc1 = cls1_w[(j + 1) * F + f];
            float wc2 = cls1_w[(j + 2) * F + f];
            float wc3 = cls1_w[(j + 3) * F + f];
            float wp0 = prop1_w[(j + 0) * F + f];
            float wp1 = prop1_w[(j + 1) * F + f];
            float wp2 = prop1_w[(j + 2) * F + f];
            float wp3 = prop1_w[(j + 3) * F + f];
#pragma unroll
            for (int i = 0; i < QH; ++i) {
                float4 y4 = *(const float4*)&sy[g * QH + i][j];
                c1[i] = fmaf(y4.x, wc0, c1[i]);
                c1[i] = fmaf(y4.y, wc1, c1[i]);
                c1[i] = fmaf(y4.z, wc2, c1[i]);
                c1[i] = fmaf(y4.w, wc3, c1[i]);
                p1[i] = fmaf(y4.x, wp0, p1[i]);
                p1[i] = fmaf(y4.y, wp1, p1[i]);
                p1[i] = fmaf(y4.z, wp2, p1[i]);
                p1[i] = fmaf(y4.w, wp3, p1[i]);
            }
        }
#pragma unroll
        for (int i = 0; i < QH; ++i) {
            sc1[g * QH + i][f] = ssp(c1[i]);
            sp1[g * QH + i][f] = ssp(p1[i]);
        }
    }
    __syncthreads();

    // ---- tails ----
    {
        int qq = tid >> 5;
        int c = tid & 31;
        int q = q0 + qq;
        if (q < Nq && c < 15) {
            if (c < 7) {
                float acc = cls2_b[c];
                for (int j = 0; j < F; ++j) acc = fmaf(sc1[qq][j], cls2_w[j * 7 + c], acc);
                out_cls[(size_t)q * 7 + c] = acc;
            } else {
                int cc = c - 7;
                float acc = prop2_b[cc];
                for (int j = 0; j < F; ++j) acc = fmaf(sp1[qq][j], prop2_w[j * 8 + cc], acc);
                out_ind[(size_t)q * 8 + cc] = acc;
            }
        }
    }
}

extern "C" void kernel_launch(void* const* d_in, const int* in_sizes, int n_in,
                              void* d_out, int out_size, void* d_ws, size_t ws_size,
                              hipStream_t stream) {
    const float* posq   = (const float*)d_in[0];
    const float* posc   = (const float*)d_in[1];
    const float* attr   = (const float*)d_in[2];
    const int*   bq     = (const int*)d_in[3];
    const int*   bc     = (const int*)d_in[4];
    const float* lin1_w = (const float*)d_in[5];
    const float* lin2_w = (const float*)d_in[6];
    const float* lin2_b = (const float*)d_in[7];
    const float* nn1_w  = (const float*)d_in[8];
    const float* nn1_b  = (const float*)d_in[9];
    const float* nn2_w  = (const float*)d_in[10];
    const float* nn2_b  = (const float*)d_in[11];
    const float* cls1_w = (const float*)d_in[12];
    const float* cls1_b = (const float*)d_in[13];
    const float* cls2_w = (const float*)d_in[14];
    const float* cls2_b = (const float*)d_in[15];
    const float* prop1_w = (const float*)d_in[16];
    const float* prop1_b = (const float*)d_in[17];
    const float* prop2_w = (const float*)d_in[18];
    const float* prop2_b = (const float*)d_in[19];
    (void)n_in; (void)out_size; (void)ws_size;

    int Nq = in_sizes[0] / 3;
    int Nc = in_sizes[1] / 3;

    char* ws = (char*)d_ws;
    size_t off = 0;
    auto alloc = [&](size_t bytes) {
        off = (off + 255) & ~(size_t)255;
        void* p = ws + off;
        off += bytes;
        return p;
    };
    int*     ctx_start = (int*)alloc((BMAX + 1) * sizeof(int));
    int*     nbr       = (int*)alloc((size_t)Nq * K * sizeof(int));
    __half*  ctx_feat  = (__half*)alloc((size_t)Nc * F * sizeof(__half));
    __half2* wt2h      = (__half2*)alloc((size_t)TAB * F * sizeof(__half2));
    float4*  posc4     = (float4*)alloc((size_t)Nc * sizeof(float4));
    __half*  attrh     = (__half*)alloc((size_t)Nc * H * sizeof(__half));
    __half*  bfragh    = (__half*)alloc((size_t)64 * 512 * sizeof(__half));

    float* out_cls = (float*)d_out;
    float* out_ind = out_cls + (size_t)Nq * 7;

    int padB  = (Nc + 255) / 256;
    int convB = (int)(((size_t)Nc * H / 8 + 255) / 256);
    int swzB  = 64;
    int featB = (Nc + 31) / 32;             // 512
    int knnB  = (Nq + 3) / 4;               // 2048
    int wtabB = TAB / WRR;                  // 256

    prep_kernel<<<dim3(1 + padB + convB + swzB), dim3(256), 0, stream>>>(
        bc, Nc, ctx_start, posc, posc4, attr, attrh, lin1_w, bfragh, padB, convB);
    knn_kernel<<<dim3(knnB), dim3(256), 0, stream>>>(posq, posc4, bq, ctx_start, nbr, Nq);
    feat_kernel<<<dim3(featB), dim3(256), 0, stream>>>(attrh, bfragh, ctx_feat, Nc);
    wtab_kernel<<<dim3(wtabB), dim3(256), 0, stream>>>(nn1_w, nn1_b, nn2_w, nn2_b, wt2h);
    agghead_kernel<<<dim3((Nq + QB - 1) / QB), dim3(256), 0, stream>>>(
        posq, posc4, nbr, ctx_feat, wt2h,
        lin2_w, lin2_b, cls1_w, cls1_b, cls2_w, cls2_b,
        prop1_w, prop1_b, prop2_w, prop2_b, out_cls, out_ind, Nq);
}

// Round 24
// 109.095 us; speedup vs baseline: 1.0991x; 1.0041x over previous
//
#include <hip/hip_runtime.h>
#include <hip/hip_fp16.h>
#include <math.h>

#define K 32
#define F 128
#define H 256
#define TAB 1024
#define QB 8
#define BMAX 16
#define RCUT2 100.0f
#define KBINS 64
#define BINCAP 2560
#define BCAP 128
#define FP 132   // padded LDS row stride
#define WRR 16   // rows per block in wtab

typedef _Float16 f16x8 __attribute__((ext_vector_type(8)));
typedef float f32x4 __attribute__((ext_vector_type(4)));

__device__ __forceinline__ float ssp(float x) {
    return fmaxf(x, 0.0f) + log1pf(expf(-fabsf(x))) - 0.69314718055994531f;
}

__device__ __forceinline__ float d2f4(float4 p, float qx, float qy, float qz) {
    float dx = qx - p.x;
    float dy = qy - p.y;
    float dz = qz - p.z;
    return fmaf(dz, dz, fmaf(dy, dy, dx * dx));
}

// ---------------- prep: seg bounds + pos pad + attr->fp16 + lin1 B-fragment swizzle ----------------
__global__ __launch_bounds__(256) void prep_kernel(const int* __restrict__ bc, int Nc,
                                                   int* __restrict__ ctx_start,
                                                   const float* __restrict__ posc,
                                                   float4* __restrict__ posc4,
                                                   const float* __restrict__ attr,
                                                   __half* __restrict__ attrh,
                                                   const float* __restrict__ lin1_w,
                                                   __half* __restrict__ bfragh,
                                                   int padB, int convB) {
    int blk = blockIdx.x;
    int tid = threadIdx.x;
    if (blk == 0) {
        if (tid <= BMAX) {
            int b = tid;
            int lo = 0, hi = Nc;
            while (lo < hi) {
                int mid = (lo + hi) >> 1;
                if (bc[mid] < b) lo = mid + 1; else hi = mid;
            }
            ctx_start[b] = lo;
        }
    } else if (blk <= padB) {
        int i = (blk - 1) * 256 + tid;
        if (i < Nc)
            posc4[i] = make_float4(posc[i * 3 + 0], posc[i * 3 + 1], posc[i * 3 + 2], 0.0f);
    } else if (blk <= padB + convB) {
        size_t base = ((size_t)(blk - 1 - padB) * 256 + tid) * 8;
        if (base < (size_t)Nc * H) {
            float4 v0 = *(const float4*)&attr[base];
            float4 v1 = *(const float4*)&attr[base + 4];
            __half2 h[4];
            h[0] = __floats2half2_rn(v0.x, v0.y);
            h[1] = __floats2half2_rn(v0.z, v0.w);
            h[2] = __floats2half2_rn(v1.x, v1.y);
            h[3] = __floats2half2_rn(v1.z, v1.w);
            *(float4*)&attrh[base] = *(float4*)h;
        }
    } else {
        // B-fragment swizzle: ts = t*8+s; element e = lane*8+j
        int ts = blk - 1 - padB - convB;     // 0..63
        int t = ts >> 3, s = ts & 7;
        for (int e = tid; e < 512; e += 256) {
            int l = e >> 3, j = e & 7;
            int k = s * 32 + (l >> 4) * 8 + j;
            int col = (l & 15) + 16 * t;
            bfragh[(size_t)ts * 512 + e] = __float2half(lin1_w[k * F + col]);
        }
    }
}

// ---------------- feat: MFMA fp16 GEMM. 512 blocks x 4 waves; wave = 32r x 32c ----------------
__global__ __launch_bounds__(256) void feat_kernel(const __half* __restrict__ attrh_,
                                                   const __half* __restrict__ bfragh_,
                                                   __half* __restrict__ ctx_feat, int Nc) {
    const _Float16* attrh = (const _Float16*)attrh_;
    const _Float16* bfragh = (const _Float16*)bfragh_;
    int tid = threadIdx.x;
    int wave = tid >> 6;
    int lane = tid & 63;
    int r0 = blockIdx.x * 32;

    f32x4 acc[2][2] = {{{0.f,0.f,0.f,0.f},{0.f,0.f,0.f,0.f}},{{0.f,0.f,0.f,0.f},{0.f,0.f,0.f,0.f}}};

    int arow[2];
#pragma unroll
    for (int rt = 0; rt < 2; ++rt) {
        int row = r0 + rt * 16 + (lane & 15);
        arow[rt] = (row < Nc) ? row : (Nc - 1);
    }
    int kbase = (lane >> 4) * 8;

    for (int s = 0; s < 8; ++s) {
        f16x8 a0 = *(const f16x8*)(attrh + (size_t)arow[0] * H + s * 32 + kbase);
        f16x8 a1 = *(const f16x8*)(attrh + (size_t)arow[1] * H + s * 32 + kbase);
#pragma unroll
        for (int ct = 0; ct < 2; ++ct) {
            int t = 2 * wave + ct;
            f16x8 b = *(const f16x8*)(bfragh + ((size_t)(t * 8 + s) * 64 + lane) * 8);
            acc[0][ct] = __builtin_amdgcn_mfma_f32_16x16x32_f16(a0, b, acc[0][ct], 0, 0, 0);
            acc[1][ct] = __builtin_amdgcn_mfma_f32_16x16x32_f16(a1, b, acc[1][ct], 0, 0, 0);
        }
    }

    // C layout: col = lane&15, row = (lane>>4)*4 + j
#pragma unroll
    for (int rt = 0; rt < 2; ++rt) {
#pragma unroll
        for (int ct = 0; ct < 2; ++ct) {
            int col = (2 * wave + ct) * 16 + (lane & 15);
#pragma unroll
            for (int j = 0; j < 4; ++j) {
                int row = r0 + rt * 16 + (lane >> 4) * 4 + j;
                if (row < Nc)
                    ctx_feat[(size_t)row * F + col] = __float2half(acc[rt][ct][j]);
            }
        }
    }
}

// ---------------- knn ----------------
__global__ __launch_bounds__(256) void knn_kernel(const float* __restrict__ posq,
                                                  const float4* __restrict__ posc4,
                                                  const int* __restrict__ bq,
                                                  const int* __restrict__ ctx_start,
                                                  int* __restrict__ nbr, int Nq) {
    __shared__ unsigned char sbin[4][BINCAP];
    __shared__ int hist[4][KBINS];
    __shared__ unsigned bkey[4][BCAP];
    __shared__ int bidx[4][BCAP];
    __shared__ int s_nwin[4], s_nbnd[4];

    int tid = threadIdx.x;
    int lane = tid & 63;
    int w = tid >> 6;
    int q = blockIdx.x * 4 + w;
    bool active = q < Nq;
    int qc = active ? q : 0;

    hist[w][lane] = 0;
    if (lane == 0) { s_nwin[w] = 0; s_nbnd[w] = 0; }

    float qx = posq[qc * 3 + 0];
    float qy = posq[qc * 3 + 1];
    float qz = posq[qc * 3 + 2];
    int b = bq[qc];
    int c0 = ctx_start[b];
    int c1 = ctx_start[b + 1];
    int seg = active ? (c1 - c0) : 0;
    __syncthreads();

    const float SCALE = (float)KBINS / RCUT2;
    int farc = -1;

    for (int i = lane; i < seg; i += 64) {
        float d2 = d2f4(posc4[c0 + i], qx, qy, qz);
        int bin = 255;
        if (d2 < RCUT2) {
            bin = (int)(d2 * SCALE);
            atomicAdd(&hist[w][bin], 1);
        }
        if (i < BINCAP) sbin[w][i] = (unsigned char)bin;
    }
    __syncthreads();

    int h = hist[w][lane];
    int inc = h;
#pragma unroll
    for (int off = 1; off < 64; off <<= 1) {
        int v = __shfl_up(inc, off);
        if (lane >= off) inc += v;
    }
    unsigned long long bal = __ballot(inc >= K);
    int T, below;
    if (bal) {
        T = __ffsll(bal) - 1;
        below = __shfl(inc, T) - __shfl(h, T);
    } else {
        T = KBINS;
        below = __shfl(inc, 63);
    }

    for (int i = lane; i < seg; i += 64) {
        int c = c0 + i;
        int bin;
        if (i < BINCAP) bin = sbin[w][i];
        else {
            float d2 = d2f4(posc4[c], qx, qy, qz);
            bin = (d2 < RCUT2) ? (int)(d2 * SCALE) : 255;
        }
        if (bin < T) {
            int p = atomicAdd(&s_nwin[w], 1);
            nbr[(size_t)q * K + p] = c;
        } else if (bin == T) {
            int p = atomicAdd(&s_nbnd[w], 1);
            if (p < BCAP) {
                float d2 = d2f4(posc4[c], qx, qy, qz);
                bkey[w][p] = __float_as_uint(d2);
                bidx[w][p] = c;
            }
        } else if (bin == 255) {
            farc = c;
        }
    }
#pragma unroll
    for (int off = 1; off < 64; off <<= 1) farc = max(farc, __shfl_xor(farc, off));
    if (farc < 0) farc = c0;
    __syncthreads();

    if (!active) return;
    int nb = min(s_nbnd[w], BCAP);
    int m = K - s_nwin[w];
    // pick m smallest by (d2, ctx_index): deterministic under atomic reordering,
    // matches jax top_k stable lowest-index tie-break.
    for (int it = 0; it < m; ++it) {
        unsigned long long bestkey = 0xFFFFFFFFFFFFFFFFull;
        int bestp = -1;
        for (int p = lane; p < nb; p += 64) {
            unsigned kk = bkey[w][p];
            if (kk != 0xFFFFFFFFu) {
                unsigned long long pk = ((unsigned long long)kk << 32) | (unsigned)bidx[w][p];
                if (pk < bestkey) { bestkey = pk; bestp = p; }
            }
        }
#pragma unroll
        for (int off = 1; off < 64; off <<= 1) {
            unsigned long long ok = __shfl_xor(bestkey, off);
            int op = __shfl_xor(bestp, off);
            if (ok < bestkey) { bestkey = ok; bestp = op; }
        }
        if (lane == 0) {
            if (bestp >= 0 && bestkey != 0xFFFFFFFFFFFFFFFFull) {
                nbr[(size_t)q * K + below + it] = (int)(bestkey & 0xFFFFFFFFu);
                bkey[w][bestp] = 0xFFFFFFFFu;
            } else {
                nbr[(size_t)q * K + below + it] = farc;   // pad: contributes 0
            }
        }
        __asm__ volatile("" ::: "memory");
    }
}

// ---------------- wtab: half2 lerp table, TAB=1024 (512 KB -> L2-resident) ----------------
__global__ __launch_bounds__(256) void wtab_kernel(const float* __restrict__ nn1_w,
                                                   const float* __restrict__ nn1_b,
                                                   const float* __restrict__ nn2_w,
                                                   const float* __restrict__ nn2_b,
                                                   __half2* __restrict__ wt2h) {
    __shared__ float sg[17][F];
    __shared__ float st[17][F];
    int t0 = blockIdx.x * WRR;
    int tid = threadIdx.x;
    int f = tid & (F - 1);
    int g = tid >> 7;

    const float delta = 10.0f / 127.0f;
    const float coeff = -0.5f / (delta * delta);
    float off = (float)f * delta;
    for (int r = g; r < 17; r += 2) {
        float dist = (float)(t0 + r) * (10.0f / (float)TAB);
        float d = dist - off;
        sg[r][f] = expf(coeff * d * d);
    }
    __syncthreads();

    float acc[9];
#pragma unroll
    for (int r = 0; r < 9; ++r) acc[r] = 0.0f;
    for (int j = 0; j < F; j += 4) {
        float w0 = nn1_w[(j + 0) * F + f];
        float w1 = nn1_w[(j + 1) * F + f];
        float w2 = nn1_w[(j + 2) * F + f];
        float w3 = nn1_w[(j + 3) * F + f];
#pragma unroll
        for (int r = 0; r < 9; ++r) {
            float4 a4 = *(const float4*)&sg[g * 8 + r][j];
            acc[r] = fmaf(a4.x, w0, acc[r]);
            acc[r] = fmaf(a4.y, w1, acc[r]);
            acc[r] = fmaf(a4.z, w2, acc[r]);
            acc[r] = fmaf(a4.w, w3, acc[r]);
        }
    }
    float b1 = nn1_b[f];
#pragma unroll
    for (int r = 0; r < 9; ++r) st[g * 8 + r][f] = ssp(acc[r] + b1);
    __syncthreads();

#pragma unroll
    for (int r = 0; r < 9; ++r) acc[r] = 0.0f;
    for (int j = 0; j < F; j += 4) {
        float w0 = nn2_w[(j + 0) * F + f];
        float w1 = nn2_w[(j + 1) * F + f];
        float w2 = nn2_w[(j + 2) * F + f];
        float w3 = nn2_w[(j + 3) * F + f];
#pragma unroll
        for (int r = 0; r < 9; ++r) {
            float4 a4 = *(const float4*)&st[g * 8 + r][j];
            acc[r] = fmaf(a4.x, w0, acc[r]);
            acc[r] = fmaf(a4.y, w1, acc[r]);
            acc[r] = fmaf(a4.z, w2, acc[r]);
            acc[r] = fmaf(a4.w, w3, acc[r]);
        }
    }
    float b2 = nn2_b[f];
#pragma unroll
    for (int i = 0; i < 8; ++i) {
        int t = t0 + g * 8 + i;
        wt2h[(size_t)t * F + f] = __floats2half2_rn(acc[i] + b2, acc[i + 1] + b2);
    }
}

// ================= fused agg + head: f-quad agg over fp16 tables =================
__global__ __launch_bounds__(256) void agghead_kernel(const float* __restrict__ posq,
                                                      const float4* __restrict__ posc4,
                                                      const int* __restrict__ nbr,
                                                      const __half* __restrict__ ctx_feat,
                                                      const __half2* __restrict__ wt2h,
                                                      const float* __restrict__ lin2_w,
                                                      const float* __restrict__ lin2_b,
                                                      const float* __restrict__ cls1_w,
                                                      const float* __restrict__ cls1_b,
                                                      const float* __restrict__ cls2_w,
                                                      const float* __restrict__ cls2_b,
                                                      const float* __restrict__ prop1_w,
                                                      const float* __restrict__ prop1_b,
                                                      const float* __restrict__ prop2_w,
                                                      const float* __restrict__ prop2_b,
                                                      float* __restrict__ out_cls,
                                                      float* __restrict__ out_ind, int Nq) {
    const int QH = QB / 2;
    int q0 = blockIdx.x * QB;
    int tid = threadIdx.x;

    __shared__ __align__(16) char sm[12672];
    float4* sedge      = (float4*)sm;                       // [256]
    float (*sa)[F]     = (float (*)[F])(sm + 4096);         // [8][128]
    float* ssc         = (float*)(sm + 8192);               // [8]
    float (*sc1)[FP]   = (float (*)[FP])(sm);               // alias (after stage A)
    float (*sp1)[FP]   = (float (*)[FP])(sm + 4224);        // alias
    float (*sy)[FP]    = (float (*)[FP])(sm + 8448);        // [8][132]

    // ---- per-edge stage ----
    {
        int qq = tid >> 5;
        int q = q0 + qq;
        if (q >= Nq) q = Nq - 1;
        int j = nbr[(size_t)q * K + (tid & 31)];
        float4 p = posc4[j];
        float dx = posq[q * 3 + 0] - p.x;
        float dy = posq[q * 3 + 1] - p.y;
        float dz = posq[q * 3 + 2] - p.z;
        float dist = sqrtf(fmaf(dz, dz, fmaf(dy, dy, dx * dx)));
        float C = 0.0f, fr = 0.0f;
        int i0 = 0;
        if (dist <= 10.0f) {
            C = 0.5f * (cosf(dist * 0.31415926535897931f) + 1.0f);
            float u = dist * ((float)TAB / 10.0f);
            i0 = (int)u;
            if (i0 > TAB - 1) i0 = TAB - 1;
            fr = u - (float)i0;
        }
        sedge[tid] = make_float4(C, fr, __int_as_float(i0 * F), __int_as_float(j * F));
        float cs = C;
#pragma unroll
        for (int off = 1; off < 32; off <<= 1) cs += __shfl_xor(cs, off);
        if ((tid & 31) == 0) ssc[qq] = cs;
    }
    __syncthreads();

    // ---- agg: f-quad per thread; 16B wt2 + 8B ctx per k covers 4 f ----
    {
        int fq = tid & 31;          // f0 = 4*fq
        int qq = tid >> 5;          // query 0..7
        int f0 = fq * 4;
        const __half2* w2b = wt2h + f0;
        const __half* cfb = ctx_feat + f0;
        float acc[4] = {0.0f, 0.0f, 0.0f, 0.0f};
#pragma unroll 4
        for (int k = 0; k < K; ++k) {
            float4 e4 = sedge[qq * K + k];
            float C = e4.x, fr = e4.y;
            int i0f = __float_as_int(e4.z);
            int jf = __float_as_int(e4.w);
            __half2 w[4];
            *(float4*)w = *(const float4*)(w2b + i0f);     // pairs for f0..f0+3
            __half2 ah[2];
            *(float2*)ah = *(const float2*)(cfb + jf);     // ctx f0..f0+3
            float2 w0 = __half22float2(w[0]);
            float2 w1 = __half22float2(w[1]);
            float2 w2 = __half22float2(w[2]);
            float2 w3 = __half22float2(w[3]);
            float2 a0 = __half22float2(ah[0]);
            float2 a1 = __half22float2(ah[1]);
            float W0 = fmaf(fr, w0.y - w0.x, w0.x);
            float W1 = fmaf(fr, w1.y - w1.x, w1.x);
            float W2 = fmaf(fr, w2.y - w2.x, w2.x);
            float W3 = fmaf(fr, w3.y - w3.x, w3.x);
            acc[0] = fmaf(C * W0, a0.x, acc[0]);
            acc[1] = fmaf(C * W1, a0.y, acc[1]);
            acc[2] = fmaf(C * W2, a1.x, acc[2]);
            acc[3] = fmaf(C * W3, a1.y, acc[3]);
        }
        *(float4*)&sa[qq][f0] = make_float4(acc[0], acc[1], acc[2], acc[3]);
    }
    __syncthreads();

    int f = tid & (F - 1);
    int g = tid >> 7;

    // ---- head stage A ----
    {
        float y[QH];
        float lb = lin2_b[f];
#pragma unroll
        for (int i = 0; i < QH; ++i) y[i] = ssc[g * QH + i] * lb;
        for (int j = 0; j < F; j += 4) {
            float w0 = lin2_w[(j + 0) * F + f];
            float w1 = lin2_w[(j + 1) * F + f];
            float w2 = lin2_w[(j + 2) * F + f];
            float w3 = lin2_w[(j + 3) * F + f];
#pragma unroll
            for (int i = 0; i < QH; ++i) {
                float4 a4 = *(const float4*)&sa[g * QH + i][j];
                y[i] = fmaf(a4.x, w0, y[i]);
                y[i] = fmaf(a4.y, w1, y[i]);
                y[i] = fmaf(a4.z, w2, y[i]);
                y[i] = fmaf(a4.w, w3, y[i]);
            }
        }
#pragma unroll
        for (int i = 0; i < QH; ++i) sy[g * QH + i][f] = y[i];
    }
    __syncthreads();   // sa/sedge/ssc dead; sc1/sp1 may overwrite

    // ---- head stage B ----
    {
        float c1[QH], p1[QH];
        float cb = cls1_b[f], pb = prop1_b[f];
#pragma unroll
        for (int i = 0; i < QH; ++i) { c1[i] = cb; p1[i] = pb; }
        for (int j = 0; j < F; j += 4) {
            float wc0 = cls1_w[(j + 0) * F + f];
            float wc1 = cls1_w[(j + 1) * F + f];
            float wc2 = cls1_w[(j + 2) * F + f];
            float wc3 = cls1_w[(j + 3) * F + f];
            float wp0 = prop1_w[(j + 0) * F + f];
            float wp1 = prop1_w[(j + 1) * F + f];
            float wp2 = prop1_w[(j + 2) * F + f];
            float wp3 = prop1_w[(j + 3) * F + f];
#pragma unroll
            for (int i = 0; i < QH; ++i) {
                float4 y4 = *(const float4*)&sy[g * QH + i][j];
                c1[i] = fmaf(y4.x, wc0, c1[i]);
                c1[i] = fmaf(y4.y, wc1, c1[i]);
                c1[i] = fmaf(y4.z, wc2, c1[i]);
                c1[i] = fmaf(y4.w, wc3, c1[i]);
                p1[i] = fmaf(y4.x, wp0, p1[i]);
                p1[i] = fmaf(y4.y, wp1, p1[i]);
                p1[i] = fmaf(y4.z, wp2, p1[i]);
                p1[i] = fmaf(y4.w, wp3, p1[i]);
            }
        }
#pragma unroll
        for (int i = 0; i < QH; ++i) {
            sc1[g * QH + i][f] = ssp(c1[i]);
            sp1[g * QH + i][f] = ssp(p1[i]);
        }
    }
    __syncthreads();

    // ---- tails ----
    {
        int qq = tid >> 5;
        int c = tid & 31;
        int q = q0 + qq;
        if (q < Nq && c < 15) {
            if (c < 7) {
                float acc = cls2_b[c];
                for (int j = 0; j < F; ++j) acc = fmaf(sc1[qq][j], cls2_w[j * 7 + c], acc);
                out_cls[(size_t)q * 7 + c] = acc;
            } else {
                int cc = c - 7;
                float acc = prop2_b[cc];
                for (int j = 0; j < F; ++j) acc = fmaf(sp1[qq][j], prop2_w[j * 8 + cc], acc);
                out_ind[(size_t)q * 8 + cc] = acc;
            }
        }
    }
}

extern "C" void kernel_launch(void* const* d_in, const int* in_sizes, int n_in,
                              void* d_out, int out_size, void* d_ws, size_t ws_size,
                              hipStream_t stream) {
    const float* posq   = (const float*)d_in[0];
    const float* posc   = (const float*)d_in[1];
    const float* attr   = (const float*)d_in[2];
    const int*   bq     = (const int*)d_in[3];
    const int*   bc     = (const int*)d_in[4];
    const float* lin1_w = (const float*)d_in[5];
    const float* lin2_w = (const float*)d_in[6];
    const float* lin2_b = (const float*)d_in[7];
    const float* nn1_w  = (const float*)d_in[8];
    const float* nn1_b  = (const float*)d_in[9];
    const float* nn2_w  = (const float*)d_in[10];
    const float* nn2_b  = (const float*)d_in[11];
    const float* cls1_w = (const float*)d_in[12];
    const float* cls1_b = (const float*)d_in[13];
    const float* cls2_w = (const float*)d_in[14];
    const float* cls2_b = (const float*)d_in[15];
    const float* prop1_w = (const float*)d_in[16];
    const float* prop1_b = (const float*)d_in[17];
    const float* prop2_w = (const float*)d_in[18];
    const float* prop2_b = (const float*)d_in[19];
    (void)n_in; (void)out_size; (void)ws_size;

    int Nq = in_sizes[0] / 3;
    int Nc = in_sizes[1] / 3;

    char* ws = (char*)d_ws;
    size_t off = 0;
    auto alloc = [&](size_t bytes) {
        off = (off + 255) & ~(size_t)255;
        void* p = ws + off;
        off += bytes;
        return p;
    };
    int*     ctx_start = (int*)alloc((BMAX + 1) * sizeof(int));
    int*     nbr       = (int*)alloc((size_t)Nq * K * sizeof(int));
    __half*  ctx_feat  = (__half*)alloc((size_t)Nc * F * sizeof(__half));
    __half2* wt2h      = (__half2*)alloc((size_t)TAB * F * sizeof(__half2));
    float4*  posc4     = (float4*)alloc((size_t)Nc * sizeof(float4));
    __half*  attrh     = (__half*)alloc((size_t)Nc * H * sizeof(__half));
    __half*  bfragh    = (__half*)alloc((size_t)64 * 512 * sizeof(__half));

    float* out_cls = (float*)d_out;
    float* out_ind = out_cls + (size_t)Nq * 7;

    int padB  = (Nc + 255) / 256;
    int convB = (int)(((size_t)Nc * H / 8 + 255) / 256);
    int swzB  = 64;
    int featB = (Nc + 31) / 32;             // 512
    int knnB  = (Nq + 3) / 4;               // 2048
    int wtabB = TAB / WRR;                  // 64

    prep_kernel<<<dim3(1 + padB + convB + swzB), dim3(256), 0, stream>>>(
        bc, Nc, ctx_start, posc, posc4, attr, attrh, lin1_w, bfragh, padB, convB);
    knn_kernel<<<dim3(knnB), dim3(256), 0, stream>>>(posq, posc4, bq, ctx_start, nbr, Nq);
    feat_kernel<<<dim3(featB), dim3(256), 0, stream>>>(attrh, bfragh, ctx_feat, Nc);
    wtab_kernel<<<dim3(wtabB), dim3(256), 0, stream>>>(nn1_w, nn1_b, nn2_w, nn2_b, wt2h);
    agghead_kernel<<<dim3((Nq + QB - 1) / QB), dim3(256), 0, stream>>>(
        posq, posc4, nbr, ctx_feat, wt2h,
        lin2_w, lin2_b, cls1_w, cls1_b, cls2_w, cls2_b,
        prop1_w, prop1_b, prop2_w, prop2_b, out_cls, out_ind, Nq);
}